// Round 1
// baseline (154.857 us; speedup 1.0000x reference)
//
#include <hip/hip_runtime.h>
#include <hip/hip_bf16.h>
#include <stdint.h>

#define N 8192
#define K 64

typedef __attribute__((ext_vector_type(8))) __bf16 bf16x8;
typedef __attribute__((ext_vector_type(4))) float f32x4;

// ws layout:
//   [0, 1MB)            : F_ll as bf16 (ushort), 8192*64
//   [1MB, 1MB+64KB)     : P1 term1 per-block partials (16384 f32)
//   [1MB+64KB, +1MB)    : P2 term2 per-block partial G (64 * 4096 f32)

__global__ __launch_bounds__(256) void convert_kernel(const float* __restrict__ in,
                                                      uint4* __restrict__ out) {
  int t = blockIdx.x * 256 + threadIdx.x;          // 65536 threads, 8 elems each
  const float4* p = (const float4*)in;
  float4 a = p[2 * t], b = p[2 * t + 1];
  float v[8] = {a.x, a.y, a.z, a.w, b.x, b.y, b.z, b.w};
  uint32_t r[8];
#pragma unroll
  for (int i = 0; i < 8; ++i) {
    uint32_t x = __float_as_uint(v[i]);
    r[i] = (x + 0x7FFFu + ((x >> 16) & 1u)) >> 16;  // RNE f32->bf16
  }
  uint4 o;
  o.x = r[0] | (r[1] << 16);
  o.y = r[2] | (r[3] << 16);
  o.z = r[4] | (r[5] << 16);
  o.w = r[6] | (r[7] << 16);
  out[t] = o;
}

// term1: each block owns a 64x64 tile of Theta; 4 waves, each a 32x32 subtile.
// S = F_I * F_J^T via mfma_f32_16x16x32_bf16 (A/B frag: row/col = lane&15,
// k = (lane>>4)*8 + e contiguous; C/D: col = lane&15, row = (lane>>4)*4 + reg).
__global__ __launch_bounds__(256) void term1_kernel(const float* __restrict__ Theta,
                                                    const ushort* __restrict__ Fb,
                                                    float* __restrict__ P1) {
  const int lane = threadIdx.x & 63;
  const int wave = threadIdx.x >> 6;
  const int bi = blockIdx.x >> 7;   // 8192/64 = 128 tiles per dim
  const int bj = blockIdx.x & 127;
  const int i0 = bi * 64 + (wave >> 1) * 32;
  const int j0 = bj * 64 + (wave & 1) * 32;
  const int l15 = lane & 15, lg = lane >> 4;

  bf16x8 afrag[2][2], bfrag[2][2];
#pragma unroll
  for (int m = 0; m < 2; ++m)
#pragma unroll
    for (int ks = 0; ks < 2; ++ks)
      afrag[m][ks] = *(const bf16x8*)&Fb[(i0 + m * 16 + l15) * K + ks * 32 + lg * 8];
#pragma unroll
  for (int n = 0; n < 2; ++n)
#pragma unroll
    for (int ks = 0; ks < 2; ++ks)
      bfrag[n][ks] = *(const bf16x8*)&Fb[(j0 + n * 16 + l15) * K + ks * 32 + lg * 8];

  f32x4 zero = {0.f, 0.f, 0.f, 0.f};
  f32x4 acc[2][2] = {{zero, zero}, {zero, zero}};
#pragma unroll
  for (int m = 0; m < 2; ++m)
#pragma unroll
    for (int n = 0; n < 2; ++n)
#pragma unroll
      for (int ks = 0; ks < 2; ++ks)
        acc[m][n] = __builtin_amdgcn_mfma_f32_16x16x32_bf16(afrag[m][ks], bfrag[n][ks],
                                                            acc[m][n], 0, 0, 0);

  float p = 0.f;
#pragma unroll
  for (int m = 0; m < 2; ++m)
#pragma unroll
    for (int n = 0; n < 2; ++n)
#pragma unroll
      for (int r = 0; r < 4; ++r) {
        size_t row = (size_t)(i0 + m * 16 + lg * 4 + r);
        size_t col = (size_t)(j0 + n * 16 + l15);
        p += acc[m][n][r] * Theta[row * N + col];
      }

#pragma unroll
  for (int off = 32; off > 0; off >>= 1) p += __shfl_down(p, off, 64);
  __shared__ float red[4];
  if (lane == 0) red[wave] = p;
  __syncthreads();
  if (threadIdx.x == 0) P1[blockIdx.x] = (red[0] + red[1]) + (red[2] + red[3]);
}

// term2: 64 blocks, each accumulates partial G (64x64, f32) over 128 rows
// (two 64-row LDS chunks). Wave w owns k in [w*16, w*16+16), lane's j = t&63.
__global__ __launch_bounds__(256) void term2_kernel(const float* __restrict__ Fll,
                                                    const float* __restrict__ Ful,
                                                    float* __restrict__ P2) {
  __shared__ float sll[64][64];
  __shared__ float sul[64][64];
  const int t = threadIdx.x;
  const int j = t & 63, kq = t >> 6;  // kq uniform within a wave -> broadcast reads
  float acc[16];
#pragma unroll
  for (int m = 0; m < 16; ++m) acc[m] = 0.f;

  for (int chunk = 0; chunk < 2; ++chunk) {
    const int r0 = blockIdx.x * 128 + chunk * 64;
    for (int i = t; i < 1024; i += 256) {  // 4096 floats per matrix = 1024 float4
      ((float4*)sll)[i] = ((const float4*)(Fll + r0 * K))[i];
      ((float4*)sul)[i] = ((const float4*)(Ful + r0 * K))[i];
    }
    __syncthreads();
    for (int r = 0; r < 64; ++r) {
      float fl = sll[r][j];
#pragma unroll
      for (int m = 0; m < 16; ++m) acc[m] += sul[r][kq * 16 + m] * fl;
    }
    __syncthreads();
  }
#pragma unroll
  for (int m = 0; m < 16; ++m)
    P2[blockIdx.x * 4096 + (kq * 16 + m) * 64 + j] = acc[m];
}

__global__ __launch_bounds__(256) void final_kernel(const float* __restrict__ P1,
                                                    const float* __restrict__ P2,
                                                    const float* __restrict__ lam,
                                                    float* __restrict__ out) {
  const int t = threadIdx.x;
  float s1 = 0.f;
  for (int i = t; i < 16384; i += 256) s1 += P1[i];
  float s2 = 0.f;
  for (int kj = t; kj < 4096; kj += 256) {
    float g = 0.f;
#pragma unroll 8
    for (int b = 0; b < 64; ++b) g += P2[b * 4096 + kj];
    s2 += g * g;
  }
  float v = s1 + lam[0] * s2;
#pragma unroll
  for (int off = 32; off > 0; off >>= 1) v += __shfl_down(v, off, 64);
  __shared__ float red[4];
  if ((t & 63) == 0) red[t >> 6] = v;
  __syncthreads();
  if (t == 0) out[0] = (red[0] + red[1]) + (red[2] + red[3]);
}

extern "C" void kernel_launch(void* const* d_in, const int* in_sizes, int n_in,
                              void* d_out, int out_size, void* d_ws, size_t ws_size,
                              hipStream_t stream) {
  const float* Fll = (const float*)d_in[0];
  const float* Ful = (const float*)d_in[1];
  const float* Theta = (const float*)d_in[2];
  const float* lam = (const float*)d_in[3];
  float* out = (float*)d_out;

  char* ws = (char*)d_ws;
  ushort* W0 = (ushort*)ws;                           // 1 MB bf16 F_ll
  float* P1 = (float*)(ws + (1u << 20));              // 64 KB
  float* P2 = (float*)(ws + (1u << 20) + (1u << 16)); // 1 MB

  convert_kernel<<<256, 256, 0, stream>>>(Fll, (uint4*)W0);
  term2_kernel<<<64, 256, 0, stream>>>(Fll, Ful, P2);
  term1_kernel<<<16384, 256, 0, stream>>>(Theta, W0, P1);
  final_kernel<<<1, 256, 0, stream>>>(P1, P2, lam, out);
}

// Round 2
// 64.903 us; speedup vs baseline: 2.3860x; 2.3860x over previous
//
#include <hip/hip_runtime.h>
#include <hip/hip_bf16.h>
#include <stdint.h>

#define N 8192
#define K 64

typedef __attribute__((ext_vector_type(8))) __bf16 bf16x8;
typedef __attribute__((ext_vector_type(4))) float f32x4;
typedef __attribute__((address_space(3))) uint8_t lds_u8;
typedef __attribute__((address_space(1))) const uint8_t glob_u8;

// ws layout:
//   [0, 1MB)               : W0 = F_ll as bf16 (ushort), 8192*64
//   [1MB, 1MB+16KB)        : P1 term1 per-block partials (4096 f32)
//   [1MB+64KB, 3MB+64KB)   : P2 term2 per-block partial G (128 * 4096 f32)
//   [0x310000, +256B)      : R1 stage2 partials (64 f32)
//   [0x310400, +256B)      : R2 stage2 partials (64 f32)

static __device__ __forceinline__ uint32_t f2bf(float f) {
  uint32_t x = __float_as_uint(f);
  return (x + 0x7FFFu + ((x >> 16) & 1u)) >> 16;  // RNE f32->bf16
}

// term2 + bf16 convert fused. 128 blocks, each owns 64 rows.
// Partial G[k][j] over its rows; also emits bf16 F_ll rows for term1.
__global__ __launch_bounds__(256) void term2_kernel(const float* __restrict__ Fll,
                                                    const float* __restrict__ Ful,
                                                    float* __restrict__ P2,
                                                    ushort* __restrict__ W0) {
  __shared__ float sll[64][64];
  __shared__ float sul[64][64];
  const int t = threadIdx.x;
  const int j = t & 63, kq = t >> 6;  // kq uniform per wave -> broadcast LDS reads
  const size_t r0 = (size_t)blockIdx.x * 64;

  for (int i = t; i < 1024; i += 256) {  // 64*64 f32 = 1024 float4 per matrix
    ((float4*)sll)[i] = ((const float4*)(Fll + r0 * K))[i];
    ((float4*)sul)[i] = ((const float4*)(Ful + r0 * K))[i];
  }
  __syncthreads();

  // emit bf16 copy of this block's F_ll rows (flat layout matches global)
  const float* sf = (const float*)sll;
#pragma unroll
  for (int h = 0; h < 2; ++h) {
    int f = t * 8 + h * 2048;
    uint32_t r[8];
#pragma unroll
    for (int e = 0; e < 8; ++e) r[e] = f2bf(sf[f + e]);
    uint4 o;
    o.x = r[0] | (r[1] << 16);
    o.y = r[2] | (r[3] << 16);
    o.z = r[4] | (r[5] << 16);
    o.w = r[6] | (r[7] << 16);
    *(uint4*)&W0[r0 * K + f] = o;
  }

  float acc[16];
#pragma unroll
  for (int m = 0; m < 16; ++m) acc[m] = 0.f;
  for (int r = 0; r < 64; ++r) {
    float fl = sll[r][j];
#pragma unroll
    for (int m = 0; m < 16; ++m) acc[m] += sul[r][kq * 16 + m] * fl;
  }
#pragma unroll
  for (int m = 0; m < 16; ++m)
    P2[(size_t)blockIdx.x * 4096 + (kq * 16 + m) * 64 + j] = acc[m];
}

// term1: block = 64 x 256 tile of Theta. Theta staged to LDS in 16-row strips
// (full 1KB contiguous per row, global_load_lds width 16, double-buffered).
// S = F_I F_J^T via mfma_f32_16x16x32_bf16; dot against LDS Theta.
// LDS row stride 260 f32 -> only 2-way bank alias (free).
__global__ __launch_bounds__(256) void term1_kernel(const float* __restrict__ Theta,
                                                    const ushort* __restrict__ Fb,
                                                    float* __restrict__ P1) {
  __shared__ float lds[2][16 * 260];
  const int t = threadIdx.x;
  const int lane = t & 63, wave = t >> 6;
  const int bi = blockIdx.x >> 5;   // 128 row-tiles
  const int bj = blockIdx.x & 31;   // 32 col-tiles
  const int i0 = bi * 64;
  const int jc0 = bj * 256;
  const int l15 = lane & 15, lg = lane >> 4;

  bf16x8 bfrag[4][2], afrag[4][2];
#pragma unroll
  for (int jf = 0; jf < 4; ++jf)
#pragma unroll
    for (int ks = 0; ks < 2; ++ks)
      bfrag[jf][ks] =
          *(const bf16x8*)&Fb[(size_t)(jc0 + wave * 64 + jf * 16 + l15) * K + ks * 32 + lg * 8];
#pragma unroll
  for (int s = 0; s < 4; ++s)
#pragma unroll
    for (int ks = 0; ks < 2; ++ks)
      afrag[s][ks] =
          *(const bf16x8*)&Fb[(size_t)(i0 + s * 16 + l15) * K + ks * 32 + lg * 8];

  float p = 0.f;

  // stage strip s: wave w loads strip-rows {w, w+4, w+8, w+12}, 1KB each.
#define STAGE(s, buf)                                                                   \
  {                                                                                     \
    _Pragma("unroll") for (int q = 0; q < 4; ++q) {                                     \
      int row = wave + 4 * q;                                                           \
      const float* g = Theta + (size_t)(i0 + (s)*16 + row) * N + jc0 + lane * 4;        \
      float* l = &lds[buf][row * 260];                                                  \
      __builtin_amdgcn_global_load_lds((glob_u8*)g, (lds_u8*)l, 16, 0, 0);              \
    }                                                                                   \
  }

  STAGE(0, 0);
  __syncthreads();
#pragma unroll
  for (int s = 0; s < 4; ++s) {
    if (s < 3) STAGE(s + 1, (s + 1) & 1);
    f32x4 zero = {0.f, 0.f, 0.f, 0.f};
    f32x4 acc[4] = {zero, zero, zero, zero};
#pragma unroll
    for (int jf = 0; jf < 4; ++jf)
#pragma unroll
      for (int ks = 0; ks < 2; ++ks)
        acc[jf] = __builtin_amdgcn_mfma_f32_16x16x32_bf16(afrag[s][ks], bfrag[jf][ks],
                                                          acc[jf], 0, 0, 0);
    const float* lb = &lds[s & 1][0];
#pragma unroll
    for (int jf = 0; jf < 4; ++jf)
#pragma unroll
      for (int r = 0; r < 4; ++r)
        p += acc[jf][r] * lb[(lg * 4 + r) * 260 + wave * 64 + jf * 16 + l15];
    __syncthreads();
  }

#pragma unroll
  for (int off = 32; off > 0; off >>= 1) p += __shfl_down(p, off, 64);
  __shared__ float red[4];
  if (lane == 0) red[wave] = p;
  __syncthreads();
  if (t == 0) P1[blockIdx.x] = (red[0] + red[1]) + (red[2] + red[3]);
}

// stage2: 64 blocks. Block b: sums P1 slice [b*64, b*64+64) and finishes
// G columns kj in [b*64, b*64+64) across the 128 term2 partials, squaring.
__global__ __launch_bounds__(256) void stage2_kernel(const float* __restrict__ P1,
                                                     const float* __restrict__ P2,
                                                     float* __restrict__ R1,
                                                     float* __restrict__ R2) {
  __shared__ float sg[4][64];
  const int t = threadIdx.x, b = blockIdx.x;
  const int l = t & 63, q = t >> 6;
  const int kj = b * 64 + l;
  float gp = 0.f;
  for (int blk = q * 32; blk < q * 32 + 32; ++blk) gp += P2[(size_t)blk * 4096 + kj];
  sg[q][l] = gp;
  float a = (t < 64) ? P1[b * 64 + t] : 0.f;
  __syncthreads();
  if (q == 0) {
    float g = (sg[0][l] + sg[1][l]) + (sg[2][l] + sg[3][l]);
    float r2 = g * g;
    float r1 = a;
#pragma unroll
    for (int off = 32; off > 0; off >>= 1) {
      r2 += __shfl_down(r2, off, 64);
      r1 += __shfl_down(r1, off, 64);
    }
    if (l == 0) {
      R1[b] = r1;
      R2[b] = r2;
    }
  }
}

__global__ void final_kernel(const float* __restrict__ R1, const float* __restrict__ R2,
                             const float* __restrict__ lam, float* __restrict__ out) {
  const int t = threadIdx.x;  // 64 threads
  float r1 = R1[t], r2 = R2[t];
#pragma unroll
  for (int off = 32; off > 0; off >>= 1) {
    r1 += __shfl_down(r1, off, 64);
    r2 += __shfl_down(r2, off, 64);
  }
  if (t == 0) out[0] = r1 + lam[0] * r2;
}

extern "C" void kernel_launch(void* const* d_in, const int* in_sizes, int n_in,
                              void* d_out, int out_size, void* d_ws, size_t ws_size,
                              hipStream_t stream) {
  const float* Fll = (const float*)d_in[0];
  const float* Ful = (const float*)d_in[1];
  const float* Theta = (const float*)d_in[2];
  const float* lam = (const float*)d_in[3];
  float* out = (float*)d_out;

  char* ws = (char*)d_ws;
  ushort* W0 = (ushort*)ws;                            // 1 MB bf16 F_ll
  float* P1 = (float*)(ws + (1u << 20));               // 16 KB
  float* P2 = (float*)(ws + (1u << 20) + (1u << 16));  // 2 MB
  float* R1 = (float*)(ws + 0x310000u);
  float* R2 = (float*)(ws + 0x310400u);

  term2_kernel<<<128, 256, 0, stream>>>(Fll, Ful, P2, W0);
  term1_kernel<<<4096, 256, 0, stream>>>(Theta, W0, P1);
  stage2_kernel<<<64, 256, 0, stream>>>(P1, P2, R1, R2);
  final_kernel<<<1, 64, 0, stream>>>(R1, R2, lam, out);
}